// Round 1
// baseline (171.480 us; speedup 1.0000x reference)
//
#include <hip/hip_runtime.h>
#include <stdint.h>

typedef unsigned short ushort_t;
typedef __attribute__((ext_vector_type(8))) short short8;   // 8 x bf16 (4 VGPRs)
typedef __attribute__((ext_vector_type(4))) float floatx4;  // MFMA accum

#define SEQ_N 2048
#define SEQ_M 2048
#define DIM_D 128
#define DIM_V 128
#define BC 64    // keys per tile

// ======================= common helpers =======================

#if __has_builtin(__builtin_amdgcn_exp2f)
#define EXP2F(x) __builtin_amdgcn_exp2f(x)
#else
#define EXP2F(x) exp2f(x)
#endif

template <int CTRL>
__device__ __forceinline__ float dpp_f(float x) {
  int xi = __builtin_bit_cast(int, x);
  int yi = __builtin_amdgcn_update_dpp(xi, xi, CTRL, 0xf, 0xf, false);
  return __builtin_bit_cast(float, yi);
}
__device__ __forceinline__ float rowmax16(float x) {
  x = fmaxf(x, dpp_f<0x128>(x));
  x = fmaxf(x, dpp_f<0x124>(x));
  x = fmaxf(x, dpp_f<0x122>(x));
  x = fmaxf(x, dpp_f<0x121>(x));
  return x;
}
__device__ __forceinline__ float rowsum16(float x) {
  x += dpp_f<0x128>(x);
  x += dpp_f<0x124>(x);
  x += dpp_f<0x122>(x);
  x += dpp_f<0x121>(x);
  return x;
}

__device__ __forceinline__ ushort_t f2bf(float f) {
  uint32_t u = __builtin_bit_cast(uint32_t, f);
  return (ushort_t)((u + 0x8000u) >> 16);
}
// pack two fp32 -> bf16 pair in ONE v_perm (3 VALU total, bit-identical to f2bf pair)
__device__ __forceinline__ uint32_t bfpack(float lo, float hi) {
  uint32_t a = __builtin_bit_cast(uint32_t, lo) + 0x8000u;
  uint32_t b = __builtin_bit_cast(uint32_t, hi) + 0x8000u;
  return __builtin_amdgcn_perm(b, a, 0x07060302u);  // {b[31:16], a[31:16]}
}

// ======================= NEW PATH (bf16 prep + gload_lds + 8-wave blocks) =======================
// LDS (ushort elements): K 2x[64][128] linear+XOR-swz, Vt 2x[128][64], P [128][64]
#define BM2 128
#define K2OFF 0
#define V2OFF 16384
#define P2OFF 32768
#define SMEM2 40960          // 81920 B -> exactly 2 blocks/CU (163840)
#define KELEMS 8192
#define VELEMS 8192

// ws layout (floats)
#define WS2_KB 0             // Kb bf16 [16][2048][128]  (masked rows zeroed)
#define WS2_VT 2097152       // Vt bf16 [16][128][2048]  (V transposed)
#define WS2_PO 4194304       // c1 partial O: 256 row-blocks x 128x128 fp32
#define WS2_M  8388608       // 512 slots x 128 rows
#define WS2_L  8454144
#define WS2_FLOATS 8519680   // * 4 = 34078720 bytes

// async 16B global->LDS; lds_base must be wave-uniform (HW adds lane*16)
__device__ __forceinline__ void stage16(const ushort_t* src, ushort_t* lds_base, int lane) {
#if __has_builtin(__builtin_amdgcn_global_load_lds)
  __builtin_amdgcn_global_load_lds(
      (const __attribute__((address_space(1))) void*)src,
      (__attribute__((address_space(3))) void*)lds_base, 16, 0, 0);
#else
  *(uint4*)(lds_base + lane * 8) = *(const uint4*)src;
#endif
}

// prep: K -> bf16 (+ padding mask), V -> bf16 transposed [b][v][m]
__global__ __launch_bounds__(256)
void prep2(const float* __restrict__ K, const float* __restrict__ Vg,
           const int* __restrict__ kpl, float* __restrict__ ws) {
  __shared__ __align__(16) ushort_t lt[64][72];
  ushort_t* Kb = (ushort_t*)(ws + WS2_KB);
  ushort_t* Vt = (ushort_t*)(ws + WS2_VT);
  const int g = blockIdx.x, tid = threadIdx.x;
  if (g < 2048) {
    const size_t e = (size_t)g * 2048 + (size_t)tid * 8;
    const int row = (int)(e >> 7);
    const int b = row >> 11, mm = row & 2047;
    const int mlimit = SEQ_M - kpl[b];
    uint4 kw = make_uint4(0u, 0u, 0u, 0u);
    if (mm < mlimit) {
      const float* p = K + e;
      float4 f0 = *(const float4*)p, f1 = *(const float4*)(p + 4);
      kw.x = bfpack(f0.x, f0.y); kw.y = bfpack(f0.z, f0.w);
      kw.z = bfpack(f1.x, f1.y); kw.w = bfpack(f1.z, f1.w);
    }
    *(uint4*)(Kb + e) = kw;
  } else {
    const int g2 = g - 2048;
    const int b = g2 >> 6;
    const int mt = (g2 & 63) >> 1;
    const int vh = (g2 & 1) * 64;
    const int mrow = tid >> 2, v0 = (tid & 3) * 16;
    const float* p = Vg + ((size_t)b * SEQ_M + (size_t)(mt * 64 + mrow)) * DIM_V + vh + v0;
    float4 f0 = *(const float4*)p, f1 = *(const float4*)(p + 4);
    float4 f2 = *(const float4*)(p + 8), f3 = *(const float4*)(p + 12);
    lt[v0 +  0][mrow] = f2bf(f0.x); lt[v0 +  1][mrow] = f2bf(f0.y);
    lt[v0 +  2][mrow] = f2bf(f0.z); lt[v0 +  3][mrow] = f2bf(f0.w);
    lt[v0 +  4][mrow] = f2bf(f1.x); lt[v0 +  5][mrow] = f2bf(f1.y);
    lt[v0 +  6][mrow] = f2bf(f1.z); lt[v0 +  7][mrow] = f2bf(f1.w);
    lt[v0 +  8][mrow] = f2bf(f2.x); lt[v0 +  9][mrow] = f2bf(f2.y);
    lt[v0 + 10][mrow] = f2bf(f2.z); lt[v0 + 11][mrow] = f2bf(f2.w);
    lt[v0 + 12][mrow] = f2bf(f3.x); lt[v0 + 13][mrow] = f2bf(f3.y);
    lt[v0 + 14][mrow] = f2bf(f3.z); lt[v0 + 15][mrow] = f2bf(f3.w);
    __syncthreads();
    const int v = tid >> 2, mo = (tid & 3) * 16;
    ushort_t* dst = Vt + ((size_t)(b * DIM_V + vh + v) * SEQ_M) + mt * 64 + mo;
    *(uint4*)(dst + 0) = *(const uint4*)&lt[v][mo];
    *(uint4*)(dst + 8) = *(const uint4*)&lt[v][mo + 8];
  }
}

// 512 wgs x 512 threads (8 waves, 16 Q-rows/wave, BM=128).
// Every row-block split into 2 key-chunks; c0 partial -> Out (unnormalized),
// c1 partial -> ws; fa2_merge combines. 2 batches pinned per XCD for L2 reuse.
__global__ __launch_bounds__(512, 4)
void fa2(const float* __restrict__ Q, const int* __restrict__ amask,
         float* __restrict__ Out, float* __restrict__ ws) {
  __shared__ __align__(16) ushort_t sm[SMEM2];
  const ushort_t* __restrict__ Kb = (const ushort_t*)(ws + WS2_KB);
  const ushort_t* __restrict__ Vt = (const ushort_t*)(ws + WS2_VT);

  const int tid = threadIdx.x;
  const int lane = tid & 63;
  const int w = tid >> 6;
  const int qd = lane >> 4;
  const int nn = lane & 15;

  const int bx = blockIdx.x;
  const int xcd = bx & 7;
  const int q8 = bx >> 3;               // 0..63
  const int b = xcd * 2 + (q8 & 1);     // 2 batches per XCD
  const int u = q8 >> 1;                // 0..31, long chunks first
  const int c = (u >= 16) ? 1 : 0;
  const int rt = c ? (31 - u) : (15 - u);

  const int flag = amask[0];
  const int ntf = flag ? (2 * rt + 2) : (SEQ_M / BC);
  const int sp  = flag ? (rt + 1) : (SEQ_M / BC / 2);
  const int jt_lo = c ? sp : 0;
  const int jt_hi = c ? ntf : sp;

  const int i0w = rt * BM2 + w * 16;
  const float c1 = 0.08838834764831845f * 1.4426950408889634f;  // scale*log2e

  // ---- Q fragments (A-layout, bf16) ----
  short8 qf[4];
  {
    const float* Qb = Q + ((size_t)b * SEQ_N + (size_t)(i0w + nn)) * DIM_D;
    union { short8 v; uint32_t u32[4]; } tq;
#pragma unroll
    for (int ks = 0; ks < 4; ++ks) {
      const float* p = Qb + ks * 32 + qd * 8;
      float4 f0 = *(const float4*)p, f1 = *(const float4*)(p + 4);
      tq.u32[0] = bfpack(f0.x, f0.y);
      tq.u32[1] = bfpack(f0.z, f0.w);
      tq.u32[2] = bfpack(f1.x, f1.y);
      tq.u32[3] = bfpack(f1.z, f1.w);
      qf[ks] = tq.v;
    }
  }

  floatx4 o[8];
#pragma unroll
  for (int vt = 0; vt < 8; ++vt) o[vt] = (floatx4)0.0f;
  float m[4], l[4];
#pragma unroll
  for (int r = 0; r < 4; ++r) { m[r] = -3.0e38f; l[r] = 0.0f; }

  const size_t kbatch = (size_t)b * (SEQ_M * DIM_D);
  const size_t vbatch = (size_t)b * ((size_t)DIM_V * SEQ_M);

  // async stage of one K tile + one V^T tile into buf (8 waves x 2 x 1KB each)
  // LDS stays linear; the XOR swizzle (16B granule, ^ (row&7)<<3 elems) is
  // applied on the GLOBAL source address (m173 pattern) and on the read side.
  auto stage = [&](int buf, int jt) {
    const int jb = jt * BC;
#pragma unroll
    for (int i = 0; i < 2; ++i) {
      const int seg = w + 8 * i;                 // 0..15 (1KB segments)
      {
        const int rrow = seg * 4 + (lane >> 4);  // K row in tile (64 rows x 256B)
        const int col  = (lane & 15) * 8;        // elem col
        const ushort_t* src = Kb + kbatch + ((size_t)(jb + rrow) << 7)
                              + (col ^ ((rrow & 7) << 3));
        stage16(src, &sm[K2OFF + buf * KELEMS + seg * 512], lane);
      }
      {
        const int vrow = seg * 8 + (lane >> 3);  // V^T row (128 rows x 128B)
        const int col  = (lane & 7) * 8;
        const ushort_t* src = Vt + vbatch + ((size_t)vrow << 11) + jb
                              + (col ^ ((vrow & 7) << 3));
        stage16(src, &sm[V2OFF + buf * VELEMS + seg * 512], lane);
      }
    }
  };

  stage(0, jt_lo);
  __syncthreads();

  const int len = jt_hi - jt_lo;
  const int swl = (nn & 7) << 3;   // read-side swizzle for rows with row&7 == nn&7
#pragma unroll 1
  for (int t = 0; t < len; ++t) {
    const int cur = t & 1;
    const int jbase = (jt_lo + t) * BC;
    if (t + 1 < len) stage(cur ^ 1, jt_lo + t + 1);

    const int kb = K2OFF + cur * KELEMS;
    const int vb = V2OFF + cur * VELEMS;

    // ---- S = Q K^T ----
    floatx4 s[4];
#pragma unroll
    for (int ct = 0; ct < 4; ++ct) s[ct] = (floatx4)0.0f;
    __builtin_amdgcn_s_setprio(1);
#pragma unroll
    for (int ks = 0; ks < 4; ++ks) {
#pragma unroll
      for (int ct = 0; ct < 4; ++ct) {
        short8 bf = *(const short8*)&sm[kb + (ct * 16 + nn) * 128
                                        + ((ks * 32 + qd * 8) ^ swl)];
        s[ct] = __builtin_amdgcn_mfma_f32_16x16x32_bf16(qf[ks], bf, s[ct], 0, 0, 0);
      }
    }
    __builtin_amdgcn_s_setprio(0);

    // ---- online softmax (16 rows/wave), P -> per-wave LDS slice ----
    {
      const bool needmask = flag && (jbase + BC - 1 > i0w);
      if (needmask) {
#pragma unroll
        for (int ct = 0; ct < 4; ++ct) {
          const int jgl = jbase + ct * 16 + nn;
#pragma unroll
          for (int r = 0; r < 4; ++r) {
            float tv = s[ct][r] * c1;
            s[ct][r] = (jgl > i0w + qd * 4 + r) ? -3.0e38f : tv;
          }
        }
      } else {
#pragma unroll
        for (int ct = 0; ct < 4; ++ct)
#pragma unroll
          for (int r = 0; r < 4; ++r) s[ct][r] *= c1;
      }
#pragma unroll
      for (int r = 0; r < 4; ++r) {
        float mr = fmaxf(fmaxf(s[0][r], s[1][r]), fmaxf(s[2][r], s[3][r]));
        mr = rowmax16(mr);
        const float mn = fmaxf(m[r], mr);
        const float alpha = EXP2F(m[r] - mn);
        m[r] = mn;
        const int prow = w * 16 + qd * 4 + r;
        const int psw = ((qd * 4 + r) & 7) << 3;
        float ps = 0.0f;
#pragma unroll
        for (int ct = 0; ct < 4; ++ct) {
          float p = EXP2F(s[ct][r] - mn);
          ps += p;
          sm[P2OFF + prow * 64 + ((ct * 16 + nn) ^ psw)] = f2bf(p);
        }
        l[r] = l[r] * alpha + ps;
#pragma unroll
        for (int vt = 0; vt < 8; ++vt) o[vt][r] *= alpha;
      }
    }

    // ---- O += P V (P rows are wave-private; in-wave lgkm ordering suffices) ----
    __builtin_amdgcn_s_setprio(1);
#pragma unroll
    for (int ks2 = 0; ks2 < 2; ++ks2) {
      short8 a = *(const short8*)&sm[P2OFF + (w * 16 + nn) * 64
                                     + ((ks2 * 32 + qd * 8) ^ swl)];
#pragma unroll
      for (int vt = 0; vt < 8; ++vt) {
        short8 vbf = *(const short8*)&sm[vb + (vt * 16 + nn) * 64
                                         + ((ks2 * 32 + qd * 8) ^ swl)];
        o[vt] = __builtin_amdgcn_mfma_f32_16x16x32_bf16(a, vbf, o[vt], 0, 0, 0);
      }
    }
    __builtin_amdgcn_s_setprio(0);

    __syncthreads();
  }

  // ---- epilogue: unnormalized partial + (m,l); merge normalizes ----
#pragma unroll
  for (int r = 0; r < 4; ++r) l[r] = rowsum16(l[r]);

  const int rb = b * 16 + rt;
  if (c == 0) {
    float* Od = Out + ((size_t)b * SEQ_N + i0w) * DIM_V;
#pragma unroll
    for (int r = 0; r < 4; ++r) {
      const int row = qd * 4 + r;
#pragma unroll
      for (int vt = 0; vt < 8; ++vt)
        Od[(size_t)row * DIM_V + vt * 16 + nn] = o[vt][r];
    }
  } else {
    float* Od = ws + WS2_PO + (size_t)rb * (BM2 * DIM_V);
#pragma unroll
    for (int r = 0; r < 4; ++r) {
      const int row = w * 16 + qd * 4 + r;
#pragma unroll
      for (int vt = 0; vt < 8; ++vt)
        Od[(size_t)row * DIM_V + vt * 16 + nn] = o[vt][r];
    }
  }
  if (nn == 0) {
    const int slot = rb * 2 + c;
#pragma unroll
    for (int r = 0; r < 4; ++r) {
      const int row = w * 16 + qd * 4 + r;
      ws[WS2_M + slot * 128 + row] = m[r];
      ws[WS2_L + slot * 128 + row] = l[r];
    }
  }
}

// merge the two chunks of every row (exp2-domain flash combine)
__global__ __launch_bounds__(256)
void fa2_merge(float* __restrict__ Out, const float* __restrict__ ws) {
  const int w = threadIdx.x >> 6, lane = threadIdx.x & 63;
  const int rowid = blockIdx.x * 4 + w;        // 0..32767
  const int rb = rowid >> 7, rr = rowid & 127;
  const int b = rb >> 4, rt = rb & 15;
  const float m1 = ws[WS2_M + (rb * 2 + 0) * 128 + rr];
  const float l1 = ws[WS2_L + (rb * 2 + 0) * 128 + rr];
  const float m2 = ws[WS2_M + (rb * 2 + 1) * 128 + rr];
  const float l2 = ws[WS2_L + (rb * 2 + 1) * 128 + rr];
  const float M = fmaxf(m1, m2);
  const float a1 = EXP2F(m1 - M), a2 = EXP2F(m2 - M);
  const float inv = 1.0f / (l1 * a1 + l2 * a2);
  float* O1 = Out + ((size_t)b * SEQ_N + (size_t)rt * BM2 + rr) * DIM_V;
  const float* O2 = ws + WS2_PO + ((size_t)rb * (BM2 * DIM_V) + (size_t)rr * DIM_V);
  float2 x1 = *(const float2*)(O1 + lane * 2);
  float2 x2 = *(const float2*)(O2 + lane * 2);
  float2 r;
  r.x = (x1.x * a1 + x2.x * a2) * inv;
  r.y = (x1.y * a1 + x2.y * a2) * inv;
  *(float2*)(O1 + lane * 2) = r;
}

// ======================= OLD PATH (verified fallback) =======================

#define KS_LD 136
#define VS_LD 72
#define PS_LD 72
#define KB(i) ((i) * 8704)
#define VB(i) (17408 + (i) * 9216)
#define P0 35840
#define SMEM_ELEMS 40448

#define WS_O_FLOATS (256 * 2 * 64 * 128)
#define WS_M_OFF    WS_O_FLOATS
#define WS_L_OFF    (WS_O_FLOATS + 32768)
#define WS_FLOATS   (WS_O_FLOATS + 65536)

__device__ __forceinline__ void process_chunk(
    const float* __restrict__ Q, const float* __restrict__ K,
    const float* __restrict__ Vg, float* __restrict__ Out,
    float* __restrict__ ws, ushort_t* __restrict__ smem,
    int b, int rt, int jt_lo, int jt_hi, int mlimit, int flag, int c, bool direct) {
  const int tid  = threadIdx.x;
  const int lane = tid & 63;
  const int w    = tid >> 6;
  const int qd   = lane >> 4;
  const int nn   = lane & 15;

  const float c1 = 0.08838834764831845f * 1.4426950408889634f;

  const int oct = tid & 15;
  const int j0  = (tid >> 4) * 4;
  const int hh  = nn >> 3;
  const int rb  = 8 * hh;

  const int i0w = rt * 64 + w * 16;
  const size_t koff = (size_t)b * SEQ_M * DIM_D;
  const size_t voff = (size_t)b * SEQ_M * DIM_V;

  short8 qf[4];
  {
    const float* Qb = Q + ((size_t)b * SEQ_N + (size_t)(i0w + nn)) * DIM_D;
    union { short8 v; uint32_t u32[4]; } t;
#pragma unroll
    for (int ks = 0; ks < 4; ++ks) {
      const float* p = Qb + ks * 32 + qd * 8;
      float4 f0 = *(const float4*)p, f1 = *(const float4*)(p + 4);
      t.u32[0] = bfpack(f0.x, f0.y);
      t.u32[1] = bfpack(f0.z, f0.w);
      t.u32[2] = bfpack(f1.x, f1.y);
      t.u32[3] = bfpack(f1.z, f1.w);
      qf[ks] = t.v;
    }
  }

  floatx4 o[8];
#pragma unroll
  for (int vt = 0; vt < 8; ++vt) o[vt] = (floatx4)0.0f;
  float m[4], l[4];
#pragma unroll
  for (int r = 0; r < 4; ++r) { m[r] = -3.0e38f; l[r] = 0.0f; }

  float4 kr[4][2], vr[4][2];

  auto stage_load = [&](int jt) {
    const int jbase = jt * BC;
#pragma unroll
    for (int r = 0; r < 4; ++r) {
      const float* kp = K  + koff + (size_t)(jbase + j0 + r) * DIM_D + oct * 8;
      kr[r][0] = *(const float4*)kp;  kr[r][1] = *(const float4*)(kp + 4);
      const float* vp = Vg + voff + (size_t)(jbase + j0 + r) * DIM_V + oct * 8;
      vr[r][0] = *(const float4*)vp;  vr[r][1] = *(const float4*)(vp + 4);
    }
  };

  auto stage_write = [&](int buf, int jt) {
    const int jbase = jt * BC;
    const int kb = KB(buf), vb = VB(buf);
#pragma unroll
    for (int r = 0; r < 4; ++r) {
      uint4 kw;
      kw.x = bfpack(kr[r][0].x, kr[r][0].y);
      kw.y = bfpack(kr[r][0].z, kr[r][0].w);
      kw.z = bfpack(kr[r][1].x, kr[r][1].y);
      kw.w = bfpack(kr[r][1].z, kr[r][1].w);
      if (jbase + j0 + r >= mlimit) kw = make_uint4(0u, 0u, 0u, 0u);
      *(uint4*)(smem + kb + (j0 + r) * KS_LD + oct * 8) = kw;
    }
    float vc[4][8];
#pragma unroll
    for (int r = 0; r < 4; ++r) {
      vc[r][0]=vr[r][0].x; vc[r][1]=vr[r][0].y; vc[r][2]=vr[r][0].z; vc[r][3]=vr[r][0].w;
      vc[r][4]=vr[r][1].x; vc[r][5]=vr[r][1].y; vc[r][6]=vr[r][1].z; vc[r][7]=vr[r][1].w;
    }
#pragma unroll
    for (int q = 0; q < 8; ++q) {
      const int p = 8 * oct + ((oct + q) & 7);
      uint2 dv;
      dv.x = bfpack(vc[0][q], vc[1][q]);
      dv.y = bfpack(vc[2][q], vc[3][q]);
      *(uint2*)(smem + vb + p * VS_LD + j0) = dv;
    }
  };

  stage_load(jt_lo);
  stage_write(0, jt_lo);
  __syncthreads();

  const int len = jt_hi - jt_lo;
#pragma unroll 1
  for (int t = 0; t < len; ++t) {
    const int jt = jt_lo + t;
    const int cur = t & 1;
    const bool more = (t + 1) < len;
    const int jbase = jt * BC;
    if (more) stage_load(jt + 1);

    const int kb = KB(cur), vb = VB(cur);

    floatx4 s[4];
#pragma unroll
    for (int ct = 0; ct < 4; ++ct) s[ct] = (floatx4)0.0f;
#pragma unroll
    for (int ks = 0; ks < 4; ++ks) {
#pragma unroll
      for (int ct = 0; ct < 4; ++ct) {
        short8 bf = *(const short8*)(smem + kb + (ct * 16 + nn) * KS_LD + ks * 32 + qd * 8);
        s[ct] = __builtin_amdgcn_mfma_f32_16x16x32_bf16(qf[ks], bf, s[ct], 0, 0, 0);
      }
    }

    {
      float tt[4][4];
      const bool needmask = flag && (jbase + BC - 1 > i0w);
#pragma unroll
      for (int ct = 0; ct < 4; ++ct)
#pragma unroll
        for (int r = 0; r < 4; ++r) {
          float tv = s[ct][r] * c1;
          if (needmask) {
            int jgl = jbase + ct * 16 + nn;
            int igl = i0w + qd * 4 + r;
            if (jgl > igl) tv = -3.0e38f;
          }
          tt[ct][r] = tv;
        }
#pragma unroll
      for (int r = 0; r < 4; ++r) {
        float mr = fmaxf(fmaxf(tt[0][r], tt[1][r]), fmaxf(tt[2][r], tt[3][r]));
        mr = rowmax16(mr);
        float mn = fmaxf(m[r], mr);
        float alpha = EXP2F(m[r] - mn);
        m[r] = mn;
        float ps = 0.0f;
#pragma unroll
        for (int ct = 0; ct < 4; ++ct) {
          float p = EXP2F(tt[ct][r] - mn);
          tt[ct][r] = p;
          ps += p;
        }
        l[r] = l[r] * alpha + ps;
#pragma unroll
        for (int vt = 0; vt < 8; ++vt) o[vt][r] *= alpha;
      }
#pragma unroll
      for (int ct = 0; ct < 4; ++ct)
#pragma unroll
        for (int r = 0; r < 4; ++r)
          smem[P0 + (w * 16 + qd * 4 + r) * PS_LD + ct * 16 + nn] = f2bf(tt[ct][r]);
    }

#pragma unroll
    for (int ks2 = 0; ks2 < 2; ++ks2) {
      short8 a = *(const short8*)(smem + P0 + (w * 16 + nn) * PS_LD + ks2 * 32 + qd * 8);
#pragma unroll
      for (int vt = 0; vt < 8; ++vt) {
        const int p = 16 * vt + rb + ((2 * vt + nn + hh) & 7);
        short8 vbf = *(const short8*)(smem + vb + p * VS_LD + ks2 * 32 + qd * 8);
        o[vt] = __builtin_amdgcn_mfma_f32_16x16x32_bf16(a, vbf, o[vt], 0, 0, 0);
      }
    }

    if (more) stage_write(cur ^ 1, jt + 1);
    __syncthreads();
  }

#pragma unroll
  for (int r = 0; r < 4; ++r) l[r] = rowsum16(l[r]);

  if (direct) {
    float* Ob = Out + ((size_t)b * SEQ_N + i0w) * DIM_V;
#pragma unroll
    for (int r = 0; r < 4; ++r) {
      float inv = 1.0f / l[r];
      int row = qd * 4 + r;
#pragma unroll
      for (int vt = 0; vt < 8; ++vt)
        Ob[(size_t)row * DIM_V + vt * 16 + nn] = o[vt][r] * inv;
    }
  } else {
    const int p = b * 16 + (rt - 16);
    const int slot = p * 2 + c;
    float* Op = ws + (size_t)slot * 64 * 128;
#pragma unroll
    for (int r = 0; r < 4; ++r) {
      int row = w * 16 + qd * 4 + r;
#pragma unroll
      for (int vt = 0; vt < 8; ++vt)
        Op[(size_t)row * 128 + vt * 16 + nn] = o[vt][r];
    }
    if (nn == 0) {
#pragma unroll
      for (int r = 0; r < 4; ++r) {
        int row = w * 16 + qd * 4 + r;
        ws[WS_M_OFF + slot * 64 + row] = m[r];
        ws[WS_L_OFF + slot * 64 + row] = l[r];
      }
    }
  }
}

__global__ __launch_bounds__(256, 2)
void fa_chunk(const float* __restrict__ Q, const float* __restrict__ K,
              const float* __restrict__ Vg, const int* __restrict__ kpl,
              const int* __restrict__ amask, float* __restrict__ Out,
              float* __restrict__ ws) {
  __shared__ __align__(16) ushort_t smem[SMEM_ELEMS];
  const int bx = blockIdx.x;
  const int b  = bx & 15;
  const int u  = bx >> 4;
  int rt, c;
  if (u < 16)      { rt = 16 + u; c = 0; }
  else if (u < 32) { rt = 47 - u; c = 1; }
  else             { rt = 47 - u; c = 0; }
  const int flag   = amask[0];
  const int mlimit = SEQ_M - kpl[b];
  const int ntiles = flag ? (rt + 1) : (SEQ_M / BC);
  const int jt_lo  = (c == 1) ? 16 : 0;
  const int jt_hi  = (c == 0 && rt >= 16) ? 16 : ntiles;
  process_chunk(Q, K, Vg, Out, ws, smem, b, rt, jt_lo, jt_hi, mlimit, flag, c, rt < 16);
}

__global__ __launch_bounds__(256)
void fa_merge(const float* __restrict__ ws, float* __restrict__ Out) {
  const int w = threadIdx.x >> 6, lane = threadIdx.x & 63;
  const int rowid = blockIdx.x * 4 + w;
  const int p = rowid >> 6, rr = rowid & 63;
  const int b = p >> 4, rt = 16 + (p & 15);
  float m1 = ws[WS_M_OFF + (p * 2 + 0) * 64 + rr];
  float l1 = ws[WS_L_OFF + (p * 2 + 0) * 64 + rr];
  float m2 = ws[WS_M_OFF + (p * 2 + 1) * 64 + rr];
  float l2 = ws[WS_L_OFF + (p * 2 + 1) * 64 + rr];
  float M  = fmaxf(m1, m2);
  float a1 = EXP2F(m1 - M), a2 = EXP2F(m2 - M);
  float inv = 1.0f / (l1 * a1 + l2 * a2);
  const float* O1 = ws + ((size_t)(p * 2 + 0) * 64 + rr) * 128;
  const float* O2 = ws + ((size_t)(p * 2 + 1) * 64 + rr) * 128;
  float2 x1 = *(const float2*)(O1 + lane * 2);
  float2 x2 = *(const float2*)(O2 + lane * 2);
  float2 r;
  r.x = (x1.x * a1 + x2.x * a2) * inv;
  r.y = (x1.y * a1 + x2.y * a2) * inv;
  *(float2*)(Out + ((size_t)b * SEQ_N + rt * 64 + rr) * 128 + lane * 2) = r;
}

__global__ __launch_bounds__(256, 2)
void fa_paired(const float* __restrict__ Q, const float* __restrict__ K,
               const float* __restrict__ Vg, const int* __restrict__ kpl,
               const int* __restrict__ amask, float* __restrict__ Out) {
  __shared__ __align__(16) ushort_t smem[SMEM_ELEMS];
  const int bx = blockIdx.x;
  const int b  = bx & 15;
  const int pp = bx >> 4;
  const int flag   = amask[0];
  const int mlimit = SEQ_M - kpl[b];
#pragma unroll 1
  for (int ph = 0; ph < 2; ++ph) {
    const int rt = ph ? (31 - pp) : pp;
    const int ntiles = flag ? (rt + 1) : (SEQ_M / BC);
    process_chunk(Q, K, Vg, Out, nullptr, smem, b, rt, 0, ntiles, mlimit, flag, 0, true);
  }
}

extern "C" void kernel_launch(void* const* d_in, const int* in_sizes, int n_in,
                              void* d_out, int out_size, void* d_ws, size_t ws_size,
                              hipStream_t stream) {
  const float* Q   = (const float*)d_in[0];
  const float* K   = (const float*)d_in[1];
  const float* V   = (const float*)d_in[2];
  const int* kpl   = (const int*)d_in[3];
  const int* amask = (const int*)d_in[4];
  float* O         = (float*)d_out;
  float* ws        = (float*)d_ws;

  if (ws_size >= (size_t)WS2_FLOATS * 4) {
    hipLaunchKernelGGL(prep2, dim3(3072), dim3(256), 0, stream, K, V, kpl, ws);
    hipLaunchKernelGGL(fa2, dim3(512), dim3(512), 0, stream, Q, amask, O, ws);
    hipLaunchKernelGGL(fa2_merge, dim3(8192), dim3(256), 0, stream, O, ws);
  } else if (ws_size >= (size_t)WS_FLOATS * 4) {
    hipLaunchKernelGGL(fa_chunk, dim3(768), dim3(256), 0, stream, Q, K, V, kpl, amask, O, ws);
    hipLaunchKernelGGL(fa_merge, dim3(4096), dim3(256), 0, stream, ws, O);
  } else {
    hipLaunchKernelGGL(fa_paired, dim3(256), dim3(256), 0, stream, Q, K, V, kpl, amask, O);
  }
}

// Round 2
// 161.681 us; speedup vs baseline: 1.0606x; 1.0606x over previous
//
#include <hip/hip_runtime.h>
#include <stdint.h>

typedef unsigned short ushort_t;
typedef __attribute__((ext_vector_type(8))) short short8;   // 8 x bf16 (4 VGPRs)
typedef __attribute__((ext_vector_type(4))) float floatx4;  // MFMA accum

#define SEQ_N 2048
#define SEQ_M 2048
#define DIM_D 128
#define DIM_V 128
#define BC 64    // keys per tile

// ======================= common helpers =======================

#if __has_builtin(__builtin_amdgcn_exp2f)
#define EXP2F(x) __builtin_amdgcn_exp2f(x)
#else
#define EXP2F(x) exp2f(x)
#endif

template <int CTRL>
__device__ __forceinline__ float dpp_f(float x) {
  int xi = __builtin_bit_cast(int, x);
  int yi = __builtin_amdgcn_update_dpp(xi, xi, CTRL, 0xf, 0xf, false);
  return __builtin_bit_cast(float, yi);
}
__device__ __forceinline__ float rowmax16(float x) {
  x = fmaxf(x, dpp_f<0x128>(x));
  x = fmaxf(x, dpp_f<0x124>(x));
  x = fmaxf(x, dpp_f<0x122>(x));
  x = fmaxf(x, dpp_f<0x121>(x));
  return x;
}
__device__ __forceinline__ float rowsum16(float x) {
  x += dpp_f<0x128>(x);
  x += dpp_f<0x124>(x);
  x += dpp_f<0x122>(x);
  x += dpp_f<0x121>(x);
  return x;
}

__device__ __forceinline__ ushort_t f2bf(float f) {
  uint32_t u = __builtin_bit_cast(uint32_t, f);
  return (ushort_t)((u + 0x8000u) >> 16);
}
// pack two fp32 -> bf16 pair in ONE v_perm (3 VALU total, bit-identical to f2bf pair)
__device__ __forceinline__ uint32_t bfpack(float lo, float hi) {
  uint32_t a = __builtin_bit_cast(uint32_t, lo) + 0x8000u;
  uint32_t b = __builtin_bit_cast(uint32_t, hi) + 0x8000u;
  return __builtin_amdgcn_perm(b, a, 0x07060302u);  // {b[31:16], a[31:16]}
}

// ======================= NEW PATH (bf16 prep + gload_lds + 8-wave blocks) =======================
// LDS (ushort elements): K 2x[64][128] linear+XOR-swz, Vt 2x[128][64], P [128][64]
#define BM2 128
#define K2OFF 0
#define V2OFF 16384
#define P2OFF 32768
#define SMEM2 40960          // 81920 B -> exactly 2 blocks/CU (163840)
#define KELEMS 8192
#define VELEMS 8192

// ws layout (floats)
#define WS2_KB 0             // Kb bf16 [16][2048][128]  (masked rows zeroed)
#define WS2_VT 2097152       // Vt bf16 [16][128][2048]  (V transposed)
#define WS2_PO 4194304       // c1 partial O: 256 row-blocks x 128x128 fp32
#define WS2_M  8388608       // 512 slots x 128 rows
#define WS2_L  8454144
#define WS2_FLOATS 8519680   // * 4 = 34078720 bytes

// async 16B global->LDS; lds_base must be wave-uniform (HW adds lane*16)
__device__ __forceinline__ void stage16(const ushort_t* src, ushort_t* lds_base, int lane) {
#if __has_builtin(__builtin_amdgcn_global_load_lds)
  __builtin_amdgcn_global_load_lds(
      (const __attribute__((address_space(1))) void*)src,
      (__attribute__((address_space(3))) void*)lds_base, 16, 0, 0);
#else
  *(uint4*)(lds_base + lane * 8) = *(const uint4*)src;
#endif
}

// prep: K -> bf16 (+ padding mask), V -> bf16 transposed [b][v][m]
__global__ __launch_bounds__(256)
void prep2(const float* __restrict__ K, const float* __restrict__ Vg,
           const int* __restrict__ kpl, float* __restrict__ ws) {
  __shared__ __align__(16) ushort_t lt[64][72];
  ushort_t* Kb = (ushort_t*)(ws + WS2_KB);
  ushort_t* Vt = (ushort_t*)(ws + WS2_VT);
  const int g = blockIdx.x, tid = threadIdx.x;
  if (g < 2048) {
    const size_t e = (size_t)g * 2048 + (size_t)tid * 8;
    const int row = (int)(e >> 7);
    const int b = row >> 11, mm = row & 2047;
    const int mlimit = SEQ_M - kpl[b];
    uint4 kw = make_uint4(0u, 0u, 0u, 0u);
    if (mm < mlimit) {
      const float* p = K + e;
      float4 f0 = *(const float4*)p, f1 = *(const float4*)(p + 4);
      kw.x = bfpack(f0.x, f0.y); kw.y = bfpack(f0.z, f0.w);
      kw.z = bfpack(f1.x, f1.y); kw.w = bfpack(f1.z, f1.w);
    }
    *(uint4*)(Kb + e) = kw;
  } else {
    const int g2 = g - 2048;
    const int b = g2 >> 6;
    const int mt = (g2 & 63) >> 1;
    const int vh = (g2 & 1) * 64;
    const int mrow = tid >> 2, v0 = (tid & 3) * 16;
    const float* p = Vg + ((size_t)b * SEQ_M + (size_t)(mt * 64 + mrow)) * DIM_V + vh + v0;
    float4 f0 = *(const float4*)p, f1 = *(const float4*)(p + 4);
    float4 f2 = *(const float4*)(p + 8), f3 = *(const float4*)(p + 12);
    lt[v0 +  0][mrow] = f2bf(f0.x); lt[v0 +  1][mrow] = f2bf(f0.y);
    lt[v0 +  2][mrow] = f2bf(f0.z); lt[v0 +  3][mrow] = f2bf(f0.w);
    lt[v0 +  4][mrow] = f2bf(f1.x); lt[v0 +  5][mrow] = f2bf(f1.y);
    lt[v0 +  6][mrow] = f2bf(f1.z); lt[v0 +  7][mrow] = f2bf(f1.w);
    lt[v0 +  8][mrow] = f2bf(f2.x); lt[v0 +  9][mrow] = f2bf(f2.y);
    lt[v0 + 10][mrow] = f2bf(f2.z); lt[v0 + 11][mrow] = f2bf(f2.w);
    lt[v0 + 12][mrow] = f2bf(f3.x); lt[v0 + 13][mrow] = f2bf(f3.y);
    lt[v0 + 14][mrow] = f2bf(f3.z); lt[v0 + 15][mrow] = f2bf(f3.w);
    __syncthreads();
    const int v = tid >> 2, mo = (tid & 3) * 16;
    ushort_t* dst = Vt + ((size_t)(b * DIM_V + vh + v) * SEQ_M) + mt * 64 + mo;
    *(uint4*)(dst + 0) = *(const uint4*)&lt[v][mo];
    *(uint4*)(dst + 8) = *(const uint4*)&lt[v][mo + 8];
  }
}

// 512 wgs x 512 threads (8 waves, 16 Q-rows/wave, BM=128).
// LOAD BALANCE: with exactly 512 co-resident blocks (2/CU) there is no backfill,
// so the two blocks sharing a CU must have COMPLEMENTARY chunk lengths.
// Plausible CU-pairings within an XCD are (q8, q8+32) and (q8, q8^1); the
// parity-mirrored map below gives len sum == 17 tiles under BOTH:
//   p=0: u<16 -> (rt=15-u, c0)  |  u>=16 -> (rt=u-16, c1)
//   p=1: u<16 -> (rt=u,    c0)  |  u>=16 -> (rt=31-u, c1)
// c0 covers key tiles [0, rt+1), c1 covers [rt+1, 2rt+2) (causal).
__global__ __launch_bounds__(512, 4)
void fa2(const float* __restrict__ Q, const int* __restrict__ amask,
         float* __restrict__ Out, float* __restrict__ ws) {
  __shared__ __align__(16) ushort_t sm[SMEM2];
  const ushort_t* __restrict__ Kb = (const ushort_t*)(ws + WS2_KB);
  const ushort_t* __restrict__ Vt = (const ushort_t*)(ws + WS2_VT);

  const int tid = threadIdx.x;
  const int lane = tid & 63;
  const int w = tid >> 6;
  const int qd = lane >> 4;
  const int nn = lane & 15;

  const int bx = blockIdx.x;
  const int xcd = bx & 7;
  const int q8 = bx >> 3;               // 0..63
  const int b = xcd * 2 + (q8 & 1);     // 2 batches per XCD (L2 reuse)
  const int u = q8 >> 1;                // 0..31
  const int p = q8 & 1;                 // batch parity
  const int c = (u >= 16) ? 1 : 0;
  int rt;
  if (p == 0) rt = c ? (u - 16) : (15 - u);
  else        rt = c ? (31 - u) : u;

  const int flag = amask[0];
  const int ntf = flag ? (2 * rt + 2) : (SEQ_M / BC);
  const int sp  = flag ? (rt + 1) : (SEQ_M / BC / 2);
  const int jt_lo = c ? sp : 0;
  const int jt_hi = c ? ntf : sp;

  const int i0w = rt * BM2 + w * 16;
  const float c1 = 0.08838834764831845f * 1.4426950408889634f;  // scale*log2e

  // ---- Q fragments (A-layout, bf16) ----
  short8 qf[4];
  {
    const float* Qb = Q + ((size_t)b * SEQ_N + (size_t)(i0w + nn)) * DIM_D;
    union { short8 v; uint32_t u32[4]; } tq;
#pragma unroll
    for (int ks = 0; ks < 4; ++ks) {
      const float* pq = Qb + ks * 32 + qd * 8;
      float4 f0 = *(const float4*)pq, f1 = *(const float4*)(pq + 4);
      tq.u32[0] = bfpack(f0.x, f0.y);
      tq.u32[1] = bfpack(f0.z, f0.w);
      tq.u32[2] = bfpack(f1.x, f1.y);
      tq.u32[3] = bfpack(f1.z, f1.w);
      qf[ks] = tq.v;
    }
  }

  floatx4 o[8];
#pragma unroll
  for (int vt = 0; vt < 8; ++vt) o[vt] = (floatx4)0.0f;
  float m[4], l[4];
#pragma unroll
  for (int r = 0; r < 4; ++r) { m[r] = -3.0e38f; l[r] = 0.0f; }

  const size_t kbatch = (size_t)b * (SEQ_M * DIM_D);
  const size_t vbatch = (size_t)b * ((size_t)DIM_V * SEQ_M);

  // async stage of one K tile + one V^T tile into buf (8 waves x 2 x 1KB each)
  // LDS stays linear; the XOR swizzle (16B granule, ^ (row&7)<<3 elems) is
  // applied on the GLOBAL source address (m173 pattern) and on the read side.
  auto stage = [&](int buf, int jt) {
    const int jb = jt * BC;
#pragma unroll
    for (int i = 0; i < 2; ++i) {
      const int seg = w + 8 * i;                 // 0..15 (1KB segments)
      {
        const int rrow = seg * 4 + (lane >> 4);  // K row in tile (64 rows x 256B)
        const int col  = (lane & 15) * 8;        // elem col
        const ushort_t* src = Kb + kbatch + ((size_t)(jb + rrow) << 7)
                              + (col ^ ((rrow & 7) << 3));
        stage16(src, &sm[K2OFF + buf * KELEMS + seg * 512], lane);
      }
      {
        const int vrow = seg * 8 + (lane >> 3);  // V^T row (128 rows x 128B)
        const int col  = (lane & 7) * 8;
        const ushort_t* src = Vt + vbatch + ((size_t)vrow << 11) + jb
                              + (col ^ ((vrow & 7) << 3));
        stage16(src, &sm[V2OFF + buf * VELEMS + seg * 512], lane);
      }
    }
  };

  stage(0, jt_lo);
  __syncthreads();

  const int len = jt_hi - jt_lo;
  const int swl = (nn & 7) << 3;   // read-side swizzle for rows with row&7 == nn&7
#pragma unroll 1
  for (int t = 0; t < len; ++t) {
    const int cur = t & 1;
    const int jbase = (jt_lo + t) * BC;
    if (t + 1 < len) stage(cur ^ 1, jt_lo + t + 1);

    const int kb = K2OFF + cur * KELEMS;
    const int vb = V2OFF + cur * VELEMS;

    // ---- S = Q K^T ----
    floatx4 s[4];
#pragma unroll
    for (int ct = 0; ct < 4; ++ct) s[ct] = (floatx4)0.0f;
    __builtin_amdgcn_s_setprio(1);
#pragma unroll
    for (int ks = 0; ks < 4; ++ks) {
#pragma unroll
      for (int ct = 0; ct < 4; ++ct) {
        short8 bf = *(const short8*)&sm[kb + (ct * 16 + nn) * 128
                                        + ((ks * 32 + qd * 8) ^ swl)];
        s[ct] = __builtin_amdgcn_mfma_f32_16x16x32_bf16(qf[ks], bf, s[ct], 0, 0, 0);
      }
    }
    __builtin_amdgcn_s_setprio(0);

    // ---- online softmax (16 rows/wave), P -> per-wave LDS slice ----
    {
      const bool needmask = flag && (jbase + BC - 1 > i0w);
      if (needmask) {
#pragma unroll
        for (int ct = 0; ct < 4; ++ct) {
          const int jgl = jbase + ct * 16 + nn;
#pragma unroll
          for (int r = 0; r < 4; ++r) {
            float tv = s[ct][r] * c1;
            s[ct][r] = (jgl > i0w + qd * 4 + r) ? -3.0e38f : tv;
          }
        }
      } else {
#pragma unroll
        for (int ct = 0; ct < 4; ++ct)
#pragma unroll
          for (int r = 0; r < 4; ++r) s[ct][r] *= c1;
      }
#pragma unroll
      for (int r = 0; r < 4; ++r) {
        float mr = fmaxf(fmaxf(s[0][r], s[1][r]), fmaxf(s[2][r], s[3][r]));
        mr = rowmax16(mr);
        const float mn = fmaxf(m[r], mr);
        const float alpha = EXP2F(m[r] - mn);
        m[r] = mn;
        const int prow = w * 16 + qd * 4 + r;
        const int psw = ((qd * 4 + r) & 7) << 3;
        float ps = 0.0f;
#pragma unroll
        for (int ct = 0; ct < 4; ++ct) {
          float pv = EXP2F(s[ct][r] - mn);
          ps += pv;
          sm[P2OFF + prow * 64 + ((ct * 16 + nn) ^ psw)] = f2bf(pv);
        }
        l[r] = l[r] * alpha + ps;
#pragma unroll
        for (int vt = 0; vt < 8; ++vt) o[vt][r] *= alpha;
      }
    }

    // ---- O += P V (P rows are wave-private; in-wave lgkm ordering suffices) ----
    __builtin_amdgcn_s_setprio(1);
#pragma unroll
    for (int ks2 = 0; ks2 < 2; ++ks2) {
      short8 a = *(const short8*)&sm[P2OFF + (w * 16 + nn) * 64
                                     + ((ks2 * 32 + qd * 8) ^ swl)];
#pragma unroll
      for (int vt = 0; vt < 8; ++vt) {
        short8 vbf = *(const short8*)&sm[vb + (vt * 16 + nn) * 64
                                         + ((ks2 * 32 + qd * 8) ^ swl)];
        o[vt] = __builtin_amdgcn_mfma_f32_16x16x32_bf16(a, vbf, o[vt], 0, 0, 0);
      }
    }
    __builtin_amdgcn_s_setprio(0);

    __syncthreads();
  }

  // ---- epilogue: unnormalized partial + (m,l); merge normalizes ----
#pragma unroll
  for (int r = 0; r < 4; ++r) l[r] = rowsum16(l[r]);

  const int rb = b * 16 + rt;
  if (c == 0) {
    float* Od = Out + ((size_t)b * SEQ_N + i0w) * DIM_V;
#pragma unroll
    for (int r = 0; r < 4; ++r) {
      const int row = qd * 4 + r;
#pragma unroll
      for (int vt = 0; vt < 8; ++vt)
        Od[(size_t)row * DIM_V + vt * 16 + nn] = o[vt][r];
    }
  } else {
    float* Od = ws + WS2_PO + (size_t)rb * (BM2 * DIM_V);
#pragma unroll
    for (int r = 0; r < 4; ++r) {
      const int row = w * 16 + qd * 4 + r;
#pragma unroll
      for (int vt = 0; vt < 8; ++vt)
        Od[(size_t)row * DIM_V + vt * 16 + nn] = o[vt][r];
    }
  }
  if (nn == 0) {
    const int slot = rb * 2 + c;
#pragma unroll
    for (int r = 0; r < 4; ++r) {
      const int row = w * 16 + qd * 4 + r;
      ws[WS2_M + slot * 128 + row] = m[r];
      ws[WS2_L + slot * 128 + row] = l[r];
    }
  }
}

// merge the two chunks of every row (exp2-domain flash combine)
__global__ __launch_bounds__(256)
void fa2_merge(float* __restrict__ Out, const float* __restrict__ ws) {
  const int w = threadIdx.x >> 6, lane = threadIdx.x & 63;
  const int rowid = blockIdx.x * 4 + w;        // 0..32767
  const int rb = rowid >> 7, rr = rowid & 127;
  const int b = rb >> 4, rt = rb & 15;
  const float m1 = ws[WS2_M + (rb * 2 + 0) * 128 + rr];
  const float l1 = ws[WS2_L + (rb * 2 + 0) * 128 + rr];
  const float m2 = ws[WS2_M + (rb * 2 + 1) * 128 + rr];
  const float l2 = ws[WS2_L + (rb * 2 + 1) * 128 + rr];
  const float M = fmaxf(m1, m2);
  const float a1 = EXP2F(m1 - M), a2 = EXP2F(m2 - M);
  const float inv = 1.0f / (l1 * a1 + l2 * a2);
  float* O1 = Out + ((size_t)b * SEQ_N + (size_t)rt * BM2 + rr) * DIM_V;
  const float* O2 = ws + WS2_PO + ((size_t)rb * (BM2 * DIM_V) + (size_t)rr * DIM_V);
  float2 x1 = *(const float2*)(O1 + lane * 2);
  float2 x2 = *(const float2*)(O2 + lane * 2);
  float2 r;
  r.x = (x1.x * a1 + x2.x * a2) * inv;
  r.y = (x1.y * a1 + x2.y * a2) * inv;
  *(float2*)(O1 + lane * 2) = r;
}

// ======================= OLD PATH (verified fallback) =======================

#define KS_LD 136
#define VS_LD 72
#define PS_LD 72
#define KB(i) ((i) * 8704)
#define VB(i) (17408 + (i) * 9216)
#define P0 35840
#define SMEM_ELEMS 40448

#define WS_O_FLOATS (256 * 2 * 64 * 128)
#define WS_M_OFF    WS_O_FLOATS
#define WS_L_OFF    (WS_O_FLOATS + 32768)
#define WS_FLOATS   (WS_O_FLOATS + 65536)

__device__ __forceinline__ void process_chunk(
    const float* __restrict__ Q, const float* __restrict__ K,
    const float* __restrict__ Vg, float* __restrict__ Out,
    float* __restrict__ ws, ushort_t* __restrict__ smem,
    int b, int rt, int jt_lo, int jt_hi, int mlimit, int flag, int c, bool direct) {
  const int tid  = threadIdx.x;
  const int lane = tid & 63;
  const int w    = tid >> 6;
  const int qd   = lane >> 4;
  const int nn   = lane & 15;

  const float c1 = 0.08838834764831845f * 1.4426950408889634f;

  const int oct = tid & 15;
  const int j0  = (tid >> 4) * 4;
  const int hh  = nn >> 3;
  const int rb  = 8 * hh;

  const int i0w = rt * 64 + w * 16;
  const size_t koff = (size_t)b * SEQ_M * DIM_D;
  const size_t voff = (size_t)b * SEQ_M * DIM_V;

  short8 qf[4];
  {
    const float* Qb = Q + ((size_t)b * SEQ_N + (size_t)(i0w + nn)) * DIM_D;
    union { short8 v; uint32_t u32[4]; } t;
#pragma unroll
    for (int ks = 0; ks < 4; ++ks) {
      const float* p = Qb + ks * 32 + qd * 8;
      float4 f0 = *(const float4*)p, f1 = *(const float4*)(p + 4);
      t.u32[0] = bfpack(f0.x, f0.y);
      t.u32[1] = bfpack(f0.z, f0.w);
      t.u32[2] = bfpack(f1.x, f1.y);
      t.u32[3] = bfpack(f1.z, f1.w);
      qf[ks] = t.v;
    }
  }

  floatx4 o[8];
#pragma unroll
  for (int vt = 0; vt < 8; ++vt) o[vt] = (floatx4)0.0f;
  float m[4], l[4];
#pragma unroll
  for (int r = 0; r < 4; ++r) { m[r] = -3.0e38f; l[r] = 0.0f; }

  float4 kr[4][2], vr[4][2];

  auto stage_load = [&](int jt) {
    const int jbase = jt * BC;
#pragma unroll
    for (int r = 0; r < 4; ++r) {
      const float* kp = K  + koff + (size_t)(jbase + j0 + r) * DIM_D + oct * 8;
      kr[r][0] = *(const float4*)kp;  kr[r][1] = *(const float4*)(kp + 4);
      const float* vp = Vg + voff + (size_t)(jbase + j0 + r) * DIM_V + oct * 8;
      vr[r][0] = *(const float4*)vp;  vr[r][1] = *(const float4*)(vp + 4);
    }
  };

  auto stage_write = [&](int buf, int jt) {
    const int jbase = jt * BC;
    const int kb = KB(buf), vb = VB(buf);
#pragma unroll
    for (int r = 0; r < 4; ++r) {
      uint4 kw;
      kw.x = bfpack(kr[r][0].x, kr[r][0].y);
      kw.y = bfpack(kr[r][0].z, kr[r][0].w);
      kw.z = bfpack(kr[r][1].x, kr[r][1].y);
      kw.w = bfpack(kr[r][1].z, kr[r][1].w);
      if (jbase + j0 + r >= mlimit) kw = make_uint4(0u, 0u, 0u, 0u);
      *(uint4*)(smem + kb + (j0 + r) * KS_LD + oct * 8) = kw;
    }
    float vc[4][8];
#pragma unroll
    for (int r = 0; r < 4; ++r) {
      vc[r][0]=vr[r][0].x; vc[r][1]=vr[r][0].y; vc[r][2]=vr[r][0].z; vc[r][3]=vr[r][0].w;
      vc[r][4]=vr[r][1].x; vc[r][5]=vr[r][1].y; vc[r][6]=vr[r][1].z; vc[r][7]=vr[r][1].w;
    }
#pragma unroll
    for (int q = 0; q < 8; ++q) {
      const int p = 8 * oct + ((oct + q) & 7);
      uint2 dv;
      dv.x = bfpack(vc[0][q], vc[1][q]);
      dv.y = bfpack(vc[2][q], vc[3][q]);
      *(uint2*)(smem + vb + p * VS_LD + j0) = dv;
    }
  };

  stage_load(jt_lo);
  stage_write(0, jt_lo);
  __syncthreads();

  const int len = jt_hi - jt_lo;
#pragma unroll 1
  for (int t = 0; t < len; ++t) {
    const int jt = jt_lo + t;
    const int cur = t & 1;
    const bool more = (t + 1) < len;
    const int jbase = jt * BC;
    if (more) stage_load(jt + 1);

    const int kb = KB(cur), vb = VB(cur);

    floatx4 s[4];
#pragma unroll
    for (int ct = 0; ct < 4; ++ct) s[ct] = (floatx4)0.0f;
#pragma unroll
    for (int ks = 0; ks < 4; ++ks) {
#pragma unroll
      for (int ct = 0; ct < 4; ++ct) {
        short8 bf = *(const short8*)(smem + kb + (ct * 16 + nn) * KS_LD + ks * 32 + qd * 8);
        s[ct] = __builtin_amdgcn_mfma_f32_16x16x32_bf16(qf[ks], bf, s[ct], 0, 0, 0);
      }
    }

    {
      float tt[4][4];
      const bool needmask = flag && (jbase + BC - 1 > i0w);
#pragma unroll
      for (int ct = 0; ct < 4; ++ct)
#pragma unroll
        for (int r = 0; r < 4; ++r) {
          float tv = s[ct][r] * c1;
          if (needmask) {
            int jgl = jbase + ct * 16 + nn;
            int igl = i0w + qd * 4 + r;
            if (jgl > igl) tv = -3.0e38f;
          }
          tt[ct][r] = tv;
        }
#pragma unroll
      for (int r = 0; r < 4; ++r) {
        float mr = fmaxf(fmaxf(tt[0][r], tt[1][r]), fmaxf(tt[2][r], tt[3][r]));
        mr = rowmax16(mr);
        float mn = fmaxf(m[r], mr);
        float alpha = EXP2F(m[r] - mn);
        m[r] = mn;
        float ps = 0.0f;
#pragma unroll
        for (int ct = 0; ct < 4; ++ct) {
          float p = EXP2F(tt[ct][r] - mn);
          tt[ct][r] = p;
          ps += p;
        }
        l[r] = l[r] * alpha + ps;
#pragma unroll
        for (int vt = 0; vt < 8; ++vt) o[vt][r] *= alpha;
      }
#pragma unroll
      for (int ct = 0; ct < 4; ++ct)
#pragma unroll
        for (int r = 0; r < 4; ++r)
          smem[P0 + (w * 16 + qd * 4 + r) * PS_LD + ct * 16 + nn] = f2bf(tt[ct][r]);
    }

#pragma unroll
    for (int ks2 = 0; ks2 < 2; ++ks2) {
      short8 a = *(const short8*)(smem + P0 + (w * 16 + nn) * PS_LD + ks2 * 32 + qd * 8);
#pragma unroll
      for (int vt = 0; vt < 8; ++vt) {
        const int p = 16 * vt + rb + ((2 * vt + nn + hh) & 7);
        short8 vbf = *(const short8*)(smem + vb + p * VS_LD + ks2 * 32 + qd * 8);
        o[vt] = __builtin_amdgcn_mfma_f32_16x16x32_bf16(a, vbf, o[vt], 0, 0, 0);
      }
    }

    if (more) stage_write(cur ^ 1, jt + 1);
    __syncthreads();
  }

#pragma unroll
  for (int r = 0; r < 4; ++r) l[r] = rowsum16(l[r]);

  if (direct) {
    float* Ob = Out + ((size_t)b * SEQ_N + i0w) * DIM_V;
#pragma unroll
    for (int r = 0; r < 4; ++r) {
      float inv = 1.0f / l[r];
      int row = qd * 4 + r;
#pragma unroll
      for (int vt = 0; vt < 8; ++vt)
        Ob[(size_t)row * DIM_V + vt * 16 + nn] = o[vt][r] * inv;
    }
  } else {
    const int p = b * 16 + (rt - 16);
    const int slot = p * 2 + c;
    float* Op = ws + (size_t)slot * 64 * 128;
#pragma unroll
    for (int r = 0; r < 4; ++r) {
      int row = w * 16 + qd * 4 + r;
#pragma unroll
      for (int vt = 0; vt < 8; ++vt)
        Op[(size_t)row * 128 + vt * 16 + nn] = o[vt][r];
    }
    if (nn == 0) {
#pragma unroll
      for (int r = 0; r < 4; ++r) {
        int row = w * 16 + qd * 4 + r;
        ws[WS_M_OFF + slot * 64 + row] = m[r];
        ws[WS_L_OFF + slot * 64 + row] = l[r];
      }
    }
  }
}

__global__ __launch_bounds__(256, 2)
void fa_chunk(const float* __restrict__ Q, const float* __restrict__ K,
              const float* __restrict__ Vg, const int* __restrict__ kpl,
              const int* __restrict__ amask, float* __restrict__ Out,
              float* __restrict__ ws) {
  __shared__ __align__(16) ushort_t smem[SMEM_ELEMS];
  const int bx = blockIdx.x;
  const int b  = bx & 15;
  const int u  = bx >> 4;
  int rt, c;
  if (u < 16)      { rt = 16 + u; c = 0; }
  else if (u < 32) { rt = 47 - u; c = 1; }
  else             { rt = 47 - u; c = 0; }
  const int flag   = amask[0];
  const int mlimit = SEQ_M - kpl[b];
  const int ntiles = flag ? (rt + 1) : (SEQ_M / BC);
  const int jt_lo  = (c == 1) ? 16 : 0;
  const int jt_hi  = (c == 0 && rt >= 16) ? 16 : ntiles;
  process_chunk(Q, K, Vg, Out, ws, smem, b, rt, jt_lo, jt_hi, mlimit, flag, c, rt < 16);
}

__global__ __launch_bounds__(256)
void fa_merge(const float* __restrict__ ws, float* __restrict__ Out) {
  const int w = threadIdx.x >> 6, lane = threadIdx.x & 63;
  const int rowid = blockIdx.x * 4 + w;
  const int p = rowid >> 6, rr = rowid & 63;
  const int b = p >> 4, rt = 16 + (p & 15);
  float m1 = ws[WS_M_OFF + (p * 2 + 0) * 64 + rr];
  float l1 = ws[WS_L_OFF + (p * 2 + 0) * 64 + rr];
  float m2 = ws[WS_M_OFF + (p * 2 + 1) * 64 + rr];
  float l2 = ws[WS_L_OFF + (p * 2 + 1) * 64 + rr];
  float M  = fmaxf(m1, m2);
  float a1 = EXP2F(m1 - M), a2 = EXP2F(m2 - M);
  float inv = 1.0f / (l1 * a1 + l2 * a2);
  const float* O1 = ws + ((size_t)(p * 2 + 0) * 64 + rr) * 128;
  const float* O2 = ws + ((size_t)(p * 2 + 1) * 64 + rr) * 128;
  float2 x1 = *(const float2*)(O1 + lane * 2);
  float2 x2 = *(const float2*)(O2 + lane * 2);
  float2 r;
  r.x = (x1.x * a1 + x2.x * a2) * inv;
  r.y = (x1.y * a1 + x2.y * a2) * inv;
  *(float2*)(Out + ((size_t)b * SEQ_N + rt * 64 + rr) * 128 + lane * 2) = r;
}

__global__ __launch_bounds__(256, 2)
void fa_paired(const float* __restrict__ Q, const float* __restrict__ K,
               const float* __restrict__ Vg, const int* __restrict__ kpl,
               const int* __restrict__ amask, float* __restrict__ Out) {
  __shared__ __align__(16) ushort_t smem[SMEM_ELEMS];
  const int bx = blockIdx.x;
  const int b  = bx & 15;
  const int pp = bx >> 4;
  const int flag   = amask[0];
  const int mlimit = SEQ_M - kpl[b];
#pragma unroll 1
  for (int ph = 0; ph < 2; ++ph) {
    const int rt = ph ? (31 - pp) : pp;
    const int ntiles = flag ? (rt + 1) : (SEQ_M / BC);
    process_chunk(Q, K, Vg, Out, nullptr, smem, b, rt, 0, ntiles, mlimit, flag, 0, true);
  }
}

extern "C" void kernel_launch(void* const* d_in, const int* in_sizes, int n_in,
                              void* d_out, int out_size, void* d_ws, size_t ws_size,
                              hipStream_t stream) {
  const float* Q   = (const float*)d_in[0];
  const float* K   = (const float*)d_in[1];
  const float* V   = (const float*)d_in[2];
  const int* kpl   = (const int*)d_in[3];
  const int* amask = (const int*)d_in[4];
  float* O         = (float*)d_out;
  float* ws        = (float*)d_ws;

  if (ws_size >= (size_t)WS2_FLOATS * 4) {
    hipLaunchKernelGGL(prep2, dim3(3072), dim3(256), 0, stream, K, V, kpl, ws);
    hipLaunchKernelGGL(fa2, dim3(512), dim3(512), 0, stream, Q, amask, O, ws);
    hipLaunchKernelGGL(fa2_merge, dim3(8192), dim3(256), 0, stream, O, ws);
  } else if (ws_size >= (size_t)WS_FLOATS * 4) {
    hipLaunchKernelGGL(fa_chunk, dim3(768), dim3(256), 0, stream, Q, K, V, kpl, amask, O, ws);
    hipLaunchKernelGGL(fa_merge, dim3(4096), dim3(256), 0, stream, ws, O);
  } else {
    hipLaunchKernelGGL(fa_paired, dim3(256), dim3(256), 0, stream, Q, K, V, kpl, amask, O);
  }
}

// Round 3
// 151.022 us; speedup vs baseline: 1.1355x; 1.0706x over previous
//
#include <hip/hip_runtime.h>
#include <stdint.h>

typedef unsigned short ushort_t;
typedef __attribute__((ext_vector_type(8))) short short8;   // 8 x bf16 (4 VGPRs)
typedef __attribute__((ext_vector_type(4))) float floatx4;  // MFMA accum

#define SEQ_N 2048
#define SEQ_M 2048
#define DIM_D 128
#define DIM_V 128
#define BC 64    // keys per tile (OLD path)
#define BC2 32   // keys per tile (NEW path)

// ======================= common helpers =======================

#if __has_builtin(__builtin_amdgcn_exp2f)
#define EXP2F(x) __builtin_amdgcn_exp2f(x)
#else
#define EXP2F(x) exp2f(x)
#endif

template <int CTRL>
__device__ __forceinline__ float dpp_f(float x) {
  int xi = __builtin_bit_cast(int, x);
  int yi = __builtin_amdgcn_update_dpp(xi, xi, CTRL, 0xf, 0xf, false);
  return __builtin_bit_cast(float, yi);
}
__device__ __forceinline__ float rowmax16(float x) {
  x = fmaxf(x, dpp_f<0x128>(x));
  x = fmaxf(x, dpp_f<0x124>(x));
  x = fmaxf(x, dpp_f<0x122>(x));
  x = fmaxf(x, dpp_f<0x121>(x));
  return x;
}
__device__ __forceinline__ float rowsum16(float x) {
  x += dpp_f<0x128>(x);
  x += dpp_f<0x124>(x);
  x += dpp_f<0x122>(x);
  x += dpp_f<0x121>(x);
  return x;
}

__device__ __forceinline__ ushort_t f2bf(float f) {
  uint32_t u = __builtin_bit_cast(uint32_t, f);
  return (ushort_t)((u + 0x8000u) >> 16);
}
// pack two fp32 -> bf16 pair in ONE v_perm (3 VALU total, bit-identical to f2bf pair)
__device__ __forceinline__ uint32_t bfpack(float lo, float hi) {
  uint32_t a = __builtin_bit_cast(uint32_t, lo) + 0x8000u;
  uint32_t b = __builtin_bit_cast(uint32_t, hi) + 0x8000u;
  return __builtin_amdgcn_perm(b, a, 0x07060302u);  // {b[31:16], a[31:16]}
}

// ======================= NEW PATH (bf16 prep + gload_lds + 4 blocks/CU) =======================
// BM=64 rows/block, BC2=32 keys/tile, 256 threads (4 waves x 16 rows).
// LDS (ushort): K 2x[32][128] (8KB ea), Vt 2x[128][32] (8KB ea), P [64][32] (4KB)
// = 36864 B -> 4 blocks/CU (4 x ~37KB <= 160KB): 4 independent barrier domains.
#define K2OFF 0
#define V2OFF 8192
#define P2OFF 16384
#define SMEM2 18432
#define KELEMS 4096
#define VELEMS 4096

// ws layout (floats) — identical bytes to round-1/2 (threshold proven available)
#define WS2_KB 0             // Kb bf16 [16][2048][128]  (masked rows zeroed)
#define WS2_VT 2097152       // Vt bf16 [16][128][2048]  (V transposed)
#define WS2_PO 4194304       // c1 partial O: 512 row-blocks x 64x128 fp32
#define WS2_M  8388608       // 1024 slots x 64 rows
#define WS2_L  8454144
#define WS2_FLOATS 8519680   // * 4 = 34078720 bytes

// async 16B global->LDS; lds_base must be wave-uniform (HW adds lane*16)
__device__ __forceinline__ void stage16(const ushort_t* src, ushort_t* lds_base, int lane) {
#if __has_builtin(__builtin_amdgcn_global_load_lds)
  __builtin_amdgcn_global_load_lds(
      (const __attribute__((address_space(1))) void*)src,
      (__attribute__((address_space(3))) void*)lds_base, 16, 0, 0);
#else
  *(uint4*)(lds_base + lane * 8) = *(const uint4*)src;
#endif
}

// prep: K -> bf16 (+ padding mask), V -> bf16 transposed [b][v][m]
__global__ __launch_bounds__(256)
void prep2(const float* __restrict__ K, const float* __restrict__ Vg,
           const int* __restrict__ kpl, float* __restrict__ ws) {
  __shared__ __align__(16) ushort_t lt[64][72];
  ushort_t* Kb = (ushort_t*)(ws + WS2_KB);
  ushort_t* Vt = (ushort_t*)(ws + WS2_VT);
  const int g = blockIdx.x, tid = threadIdx.x;
  if (g < 2048) {
    const size_t e = (size_t)g * 2048 + (size_t)tid * 8;
    const int row = (int)(e >> 7);
    const int b = row >> 11, mm = row & 2047;
    const int mlimit = SEQ_M - kpl[b];
    uint4 kw = make_uint4(0u, 0u, 0u, 0u);
    if (mm < mlimit) {
      const float* p = K + e;
      float4 f0 = *(const float4*)p, f1 = *(const float4*)(p + 4);
      kw.x = bfpack(f0.x, f0.y); kw.y = bfpack(f0.z, f0.w);
      kw.z = bfpack(f1.x, f1.y); kw.w = bfpack(f1.z, f1.w);
    }
    *(uint4*)(Kb + e) = kw;
  } else {
    const int g2 = g - 2048;
    const int b = g2 >> 6;
    const int mt = (g2 & 63) >> 1;
    const int vh = (g2 & 1) * 64;
    const int mrow = tid >> 2, v0 = (tid & 3) * 16;
    const float* p = Vg + ((size_t)b * SEQ_M + (size_t)(mt * 64 + mrow)) * DIM_V + vh + v0;
    float4 f0 = *(const float4*)p, f1 = *(const float4*)(p + 4);
    float4 f2 = *(const float4*)(p + 8), f3 = *(const float4*)(p + 12);
    lt[v0 +  0][mrow] = f2bf(f0.x); lt[v0 +  1][mrow] = f2bf(f0.y);
    lt[v0 +  2][mrow] = f2bf(f0.z); lt[v0 +  3][mrow] = f2bf(f0.w);
    lt[v0 +  4][mrow] = f2bf(f1.x); lt[v0 +  5][mrow] = f2bf(f1.y);
    lt[v0 +  6][mrow] = f2bf(f1.z); lt[v0 +  7][mrow] = f2bf(f1.w);
    lt[v0 +  8][mrow] = f2bf(f2.x); lt[v0 +  9][mrow] = f2bf(f2.y);
    lt[v0 + 10][mrow] = f2bf(f2.z); lt[v0 + 11][mrow] = f2bf(f2.w);
    lt[v0 + 12][mrow] = f2bf(f3.x); lt[v0 + 13][mrow] = f2bf(f3.y);
    lt[v0 + 14][mrow] = f2bf(f3.z); lt[v0 + 15][mrow] = f2bf(f3.w);
    __syncthreads();
    const int v = tid >> 2, mo = (tid & 3) * 16;
    ushort_t* dst = Vt + ((size_t)(b * DIM_V + vh + v) * SEQ_M) + mt * 64 + mo;
    *(uint4*)(dst + 0) = *(const uint4*)&lt[v][mo];
    *(uint4*)(dst + 8) = *(const uint4*)&lt[v][mo + 8];
  }
}

// 1024 wgs x 256 threads. Each (b, rt[0..31], chunk c) handles 64 Q-rows.
// Causal: ntf = 2rt+2 key-tiles; c0 = [0, rt+1) -> Out (unnormalized),
// c1 = [rt+1, 2rt+2) -> ws partial; merge combines. 4 blocks/CU.
// Balance: slots s=q8>>5 give complementary lens under stride-32 pairing
// (sum 66 per CU-set) and p-mirror gives sum 17 under stride-1 pairing.
__global__ __launch_bounds__(256, 4)
void fa2(const float* __restrict__ Q, const int* __restrict__ amask,
         float* __restrict__ Out, float* __restrict__ ws) {
  __shared__ __align__(16) ushort_t sm[SMEM2];
  const ushort_t* __restrict__ Kb = (const ushort_t*)(ws + WS2_KB);
  const ushort_t* __restrict__ Vt = (const ushort_t*)(ws + WS2_VT);

  const int tid = threadIdx.x;
  const int lane = tid & 63;
  const int w = tid >> 6;               // 0..3
  const int qd = lane >> 4;
  const int nn = lane & 15;

  const int bx = blockIdx.x;            // 0..1023
  const int xcd = bx & 7;
  const int q8 = bx >> 3;               // 0..127
  const int s  = q8 >> 5;               // 0..3 co-residency slot
  const int v  = q8 & 31;
  const int p  = v & 1;                 // batch parity
  const int j  = v >> 1;                // 0..15
  const int b  = xcd * 2 + p;           // 2 batches per XCD (L2 reuse)
  const int jj = p ? (15 - j) : j;
  int rt, c;
  if (s == 0)      { rt = jj;      c = 0; }
  else if (s == 1) { rt = 31 - jj; c = 0; }
  else if (s == 2) { rt = 16 + jj; c = 1; }
  else             { rt = 15 - jj; c = 1; }

  const int flag = amask[0];
  const int ntf = flag ? (2 * rt + 2) : (SEQ_M / BC2);
  const int sp  = flag ? (rt + 1) : (SEQ_M / BC2 / 2);
  const int jt_lo = c ? sp : 0;
  const int jt_hi = c ? ntf : sp;

  const int i0w = rt * 64 + w * 16;
  const float c1 = 0.08838834764831845f * 1.4426950408889634f;  // scale*log2e

  // ---- Q fragments (A-layout, bf16) ----
  short8 qf[4];
  {
    const float* Qb = Q + ((size_t)b * SEQ_N + (size_t)(i0w + nn)) * DIM_D;
    union { short8 v; uint32_t u32[4]; } tq;
#pragma unroll
    for (int ks = 0; ks < 4; ++ks) {
      const float* pq = Qb + ks * 32 + qd * 8;
      float4 f0 = *(const float4*)pq, f1 = *(const float4*)(pq + 4);
      tq.u32[0] = bfpack(f0.x, f0.y);
      tq.u32[1] = bfpack(f0.z, f0.w);
      tq.u32[2] = bfpack(f1.x, f1.y);
      tq.u32[3] = bfpack(f1.z, f1.w);
      qf[ks] = tq.v;
    }
  }

  floatx4 o[8];
#pragma unroll
  for (int vt = 0; vt < 8; ++vt) o[vt] = (floatx4)0.0f;
  float m[4], l[4];
#pragma unroll
  for (int r = 0; r < 4; ++r) { m[r] = -3.0e38f; l[r] = 0.0f; }

  const size_t kbatch = (size_t)b * (SEQ_M * DIM_D);
  const size_t vbatch = (size_t)b * ((size_t)DIM_V * SEQ_M);

  // async stage of one K tile (32x128) + one V^T tile (128x32) into buf.
  // 4 waves x 2 segs x (1 K + 1 V) gload_lds of 1KB. LDS linear; swizzles
  // applied on the GLOBAL source (m173): K granule ^= (row&7), V granule
  // (of 4 per 64B row) ^= (row>>2)&3.
  auto stage = [&](int buf, int jt) {
    const int jb = jt * BC2;
#pragma unroll
    for (int i = 0; i < 2; ++i) {
      const int seg = w * 2 + i;                 // 0..7 (1KB segments)
      {
        const int rrow = seg * 4 + (lane >> 4);  // K row in tile (32 rows x 256B)
        const int col  = ((lane & 15) * 8) ^ ((rrow & 7) << 3);
        const ushort_t* src = Kb + kbatch + ((size_t)(jb + rrow) << 7) + col;
        stage16(src, &sm[K2OFF + buf * KELEMS + seg * 512], lane);
      }
      {
        const int vrow = seg * 16 + (lane >> 2); // V^T row (128 rows x 64B)
        const int colg = (lane & 3) ^ ((lane >> 4) & 3);  // == (lane&3)^((vrow>>2)&3)
        const ushort_t* src = Vt + vbatch + ((size_t)vrow << 11) + jb + colg * 8;
        stage16(src, &sm[V2OFF + buf * VELEMS + seg * 512], lane);
      }
    }
  };

  stage(0, jt_lo);
  __syncthreads();

  const int len = jt_hi - jt_lo;
  const int swl = (nn & 7) << 3;          // K read swizzle (row&7 == nn&7)
  const int vsw = ((nn >> 2) & 3) << 3;   // V/P read swizzle ((row>>2)&3 == (nn>>2)&3)
#pragma unroll 1
  for (int t = 0; t < len; ++t) {
    const int cur = t & 1;
    const int jbase = (jt_lo + t) * BC2;
    if (t + 1 < len) stage(cur ^ 1, jt_lo + t + 1);

    const int kb = K2OFF + cur * KELEMS;
    const int vb = V2OFF + cur * VELEMS;

    // ---- S = Q K^T (16 rows x 32 keys per wave) ----
    floatx4 sx[2];
#pragma unroll
    for (int ct = 0; ct < 2; ++ct) sx[ct] = (floatx4)0.0f;
    __builtin_amdgcn_s_setprio(1);
#pragma unroll
    for (int ks = 0; ks < 4; ++ks) {
#pragma unroll
      for (int ct = 0; ct < 2; ++ct) {
        short8 bf = *(const short8*)&sm[kb + (ct * 16 + nn) * 128
                                        + ((ks * 32 + qd * 8) ^ swl)];
        sx[ct] = __builtin_amdgcn_mfma_f32_16x16x32_bf16(qf[ks], bf, sx[ct], 0, 0, 0);
      }
    }
    __builtin_amdgcn_s_setprio(0);

    // ---- online softmax (16 rows/wave), defer-max (T13, THR=8) ----
    {
      const bool needmask = flag && (jbase + BC2 - 1 > i0w);
      if (needmask) {
#pragma unroll
        for (int ct = 0; ct < 2; ++ct) {
          const int jgl = jbase + ct * 16 + nn;
#pragma unroll
          for (int r = 0; r < 4; ++r) {
            float tv = sx[ct][r] * c1;
            sx[ct][r] = (jgl > i0w + qd * 4 + r) ? -3.0e38f : tv;
          }
        }
      } else {
#pragma unroll
        for (int ct = 0; ct < 2; ++ct)
#pragma unroll
          for (int r = 0; r < 4; ++r) sx[ct][r] *= c1;
      }
      float mr4[4];
#pragma unroll
      for (int r = 0; r < 4; ++r) mr4[r] = rowmax16(fmaxf(sx[0][r], sx[1][r]));
      bool need = false;
#pragma unroll
      for (int r = 0; r < 4; ++r) need = need || (mr4[r] > m[r] + 8.0f);
      if (__any(need ? 1 : 0)) {
#pragma unroll
        for (int r = 0; r < 4; ++r) {
          const float mn = fmaxf(m[r], mr4[r]);
          const float alpha = EXP2F(m[r] - mn);
          m[r] = mn;
          l[r] *= alpha;
#pragma unroll
          for (int vt = 0; vt < 8; ++vt) o[vt][r] *= alpha;
        }
      }
#pragma unroll
      for (int r = 0; r < 4; ++r) {
        const int prow = w * 16 + qd * 4 + r;
        float p0 = EXP2F(sx[0][r] - m[r]);
        float p1 = EXP2F(sx[1][r] - m[r]);
        l[r] += p0 + p1;
        sm[P2OFF + prow * 32 + ((0 * 16 + nn) ^ (qd << 3))] = f2bf(p0);
        sm[P2OFF + prow * 32 + ((1 * 16 + nn) ^ (qd << 3))] = f2bf(p1);
      }
    }

    // ---- O += P V (P rows wave-private; in-wave lgkm ordering suffices) ----
    __builtin_amdgcn_s_setprio(1);
    {
      short8 a = *(const short8*)&sm[P2OFF + (w * 16 + nn) * 32 + ((qd * 8) ^ vsw)];
#pragma unroll
      for (int vt = 0; vt < 8; ++vt) {
        short8 vbf = *(const short8*)&sm[vb + (vt * 16 + nn) * 32 + ((qd * 8) ^ vsw)];
        o[vt] = __builtin_amdgcn_mfma_f32_16x16x32_bf16(a, vbf, o[vt], 0, 0, 0);
      }
    }
    __builtin_amdgcn_s_setprio(0);

    __syncthreads();
  }

  // ---- epilogue: unnormalized partial + (m,l); merge normalizes ----
#pragma unroll
  for (int r = 0; r < 4; ++r) l[r] = rowsum16(l[r]);

  const int rb = b * 32 + rt;             // 0..511
  if (c == 0) {
    float* Od = Out + ((size_t)b * SEQ_N + i0w) * DIM_V;
#pragma unroll
    for (int r = 0; r < 4; ++r) {
      const int row = qd * 4 + r;
#pragma unroll
      for (int vt = 0; vt < 8; ++vt)
        Od[(size_t)row * DIM_V + vt * 16 + nn] = o[vt][r];
    }
  } else {
    float* Od = ws + WS2_PO + (size_t)rb * (64 * DIM_V);
#pragma unroll
    for (int r = 0; r < 4; ++r) {
      const int row = w * 16 + qd * 4 + r;
#pragma unroll
      for (int vt = 0; vt < 8; ++vt)
        Od[(size_t)row * DIM_V + vt * 16 + nn] = o[vt][r];
    }
  }
  if (nn == 0) {
    const int slot = rb * 2 + c;
#pragma unroll
    for (int r = 0; r < 4; ++r) {
      const int row = w * 16 + qd * 4 + r;
      ws[WS2_M + slot * 64 + row] = m[r];
      ws[WS2_L + slot * 64 + row] = l[r];
    }
  }
}

// merge the two chunks of every row (exp2-domain flash combine)
__global__ __launch_bounds__(256)
void fa2_merge(float* __restrict__ Out, const float* __restrict__ ws) {
  const int w = threadIdx.x >> 6, lane = threadIdx.x & 63;
  const int rowid = blockIdx.x * 4 + w;        // 0..32767
  const int rb = rowid >> 6, rr = rowid & 63;
  const int b = rb >> 5, rt = rb & 31;
  const float m1 = ws[WS2_M + (rb * 2 + 0) * 64 + rr];
  const float l1 = ws[WS2_L + (rb * 2 + 0) * 64 + rr];
  const float m2 = ws[WS2_M + (rb * 2 + 1) * 64 + rr];
  const float l2 = ws[WS2_L + (rb * 2 + 1) * 64 + rr];
  const float M = fmaxf(m1, m2);
  const float a1 = EXP2F(m1 - M), a2 = EXP2F(m2 - M);
  const float inv = 1.0f / (l1 * a1 + l2 * a2);
  float* O1 = Out + ((size_t)b * SEQ_N + (size_t)rt * 64 + rr) * DIM_V;
  const float* O2 = ws + WS2_PO + (size_t)rb * (64 * DIM_V) + (size_t)rr * DIM_V;
  float2 x1 = *(const float2*)(O1 + lane * 2);
  float2 x2 = *(const float2*)(O2 + lane * 2);
  float2 r;
  r.x = (x1.x * a1 + x2.x * a2) * inv;
  r.y = (x1.y * a1 + x2.y * a2) * inv;
  *(float2*)(O1 + lane * 2) = r;
}

// ======================= OLD PATH (verified fallback) =======================

#define KS_LD 136
#define VS_LD 72
#define PS_LD 72
#define KB(i) ((i) * 8704)
#define VB(i) (17408 + (i) * 9216)
#define P0 35840
#define SMEM_ELEMS 40448

#define WS_O_FLOATS (256 * 2 * 64 * 128)
#define WS_M_OFF    WS_O_FLOATS
#define WS_L_OFF    (WS_O_FLOATS + 32768)
#define WS_FLOATS   (WS_O_FLOATS + 65536)

__device__ __forceinline__ void process_chunk(
    const float* __restrict__ Q, const float* __restrict__ K,
    const float* __restrict__ Vg, float* __restrict__ Out,
    float* __restrict__ ws, ushort_t* __restrict__ smem,
    int b, int rt, int jt_lo, int jt_hi, int mlimit, int flag, int c, bool direct) {
  const int tid  = threadIdx.x;
  const int lane = tid & 63;
  const int w    = tid >> 6;
  const int qd   = lane >> 4;
  const int nn   = lane & 15;

  const float c1 = 0.08838834764831845f * 1.4426950408889634f;

  const int oct = tid & 15;
  const int j0  = (tid >> 4) * 4;
  const int hh  = nn >> 3;
  const int rb  = 8 * hh;

  const int i0w = rt * 64 + w * 16;
  const size_t koff = (size_t)b * SEQ_M * DIM_D;
  const size_t voff = (size_t)b * SEQ_M * DIM_V;

  short8 qf[4];
  {
    const float* Qb = Q + ((size_t)b * SEQ_N + (size_t)(i0w + nn)) * DIM_D;
    union { short8 v; uint32_t u32[4]; } t;
#pragma unroll
    for (int ks = 0; ks < 4; ++ks) {
      const float* p = Qb + ks * 32 + qd * 8;
      float4 f0 = *(const float4*)p, f1 = *(const float4*)(p + 4);
      t.u32[0] = bfpack(f0.x, f0.y);
      t.u32[1] = bfpack(f0.z, f0.w);
      t.u32[2] = bfpack(f1.x, f1.y);
      t.u32[3] = bfpack(f1.z, f1.w);
      qf[ks] = t.v;
    }
  }

  floatx4 o[8];
#pragma unroll
  for (int vt = 0; vt < 8; ++vt) o[vt] = (floatx4)0.0f;
  float m[4], l[4];
#pragma unroll
  for (int r = 0; r < 4; ++r) { m[r] = -3.0e38f; l[r] = 0.0f; }

  float4 kr[4][2], vr[4][2];

  auto stage_load = [&](int jt) {
    const int jbase = jt * BC;
#pragma unroll
    for (int r = 0; r < 4; ++r) {
      const float* kp = K  + koff + (size_t)(jbase + j0 + r) * DIM_D + oct * 8;
      kr[r][0] = *(const float4*)kp;  kr[r][1] = *(const float4*)(kp + 4);
      const float* vp = Vg + voff + (size_t)(jbase + j0 + r) * DIM_V + oct * 8;
      vr[r][0] = *(const float4*)vp;  vr[r][1] = *(const float4*)(vp + 4);
    }
  };

  auto stage_write = [&](int buf, int jt) {
    const int jbase = jt * BC;
    const int kb = KB(buf), vb = VB(buf);
#pragma unroll
    for (int r = 0; r < 4; ++r) {
      uint4 kw;
      kw.x = bfpack(kr[r][0].x, kr[r][0].y);
      kw.y = bfpack(kr[r][0].z, kr[r][0].w);
      kw.z = bfpack(kr[r][1].x, kr[r][1].y);
      kw.w = bfpack(kr[r][1].z, kr[r][1].w);
      if (jbase + j0 + r >= mlimit) kw = make_uint4(0u, 0u, 0u, 0u);
      *(uint4*)(smem + kb + (j0 + r) * KS_LD + oct * 8) = kw;
    }
    float vc[4][8];
#pragma unroll
    for (int r = 0; r < 4; ++r) {
      vc[r][0]=vr[r][0].x; vc[r][1]=vr[r][0].y; vc[r][2]=vr[r][0].z; vc[r][3]=vr[r][0].w;
      vc[r][4]=vr[r][1].x; vc[r][5]=vr[r][1].y; vc[r][6]=vr[r][1].z; vc[r][7]=vr[r][1].w;
    }
#pragma unroll
    for (int q = 0; q < 8; ++q) {
      const int p = 8 * oct + ((oct + q) & 7);
      uint2 dv;
      dv.x = bfpack(vc[0][q], vc[1][q]);
      dv.y = bfpack(vc[2][q], vc[3][q]);
      *(uint2*)(smem + vb + p * VS_LD + j0) = dv;
    }
  };

  stage_load(jt_lo);
  stage_write(0, jt_lo);
  __syncthreads();

  const int len = jt_hi - jt_lo;
#pragma unroll 1
  for (int t = 0; t < len; ++t) {
    const int jt = jt_lo + t;
    const int cur = t & 1;
    const bool more = (t + 1) < len;
    const int jbase = jt * BC;
    if (more) stage_load(jt + 1);

    const int kb = KB(cur), vb = VB(cur);

    floatx4 s[4];
#pragma unroll
    for (int ct = 0; ct < 4; ++ct) s[ct] = (floatx4)0.0f;
#pragma unroll
    for (int ks = 0; ks < 4; ++ks) {
#pragma unroll
      for (int ct = 0; ct < 4; ++ct) {
        short8 bf = *(const short8*)(smem + kb + (ct * 16 + nn) * KS_LD + ks * 32 + qd * 8);
        s[ct] = __builtin_amdgcn_mfma_f32_16x16x32_bf16(qf[ks], bf, s[ct], 0, 0, 0);
      }
    }

    {
      float tt[4][4];
      const bool needmask = flag && (jbase + BC - 1 > i0w);
#pragma unroll
      for (int ct = 0; ct < 4; ++ct)
#pragma unroll
        for (int r = 0; r < 4; ++r) {
          float tv = s[ct][r] * c1;
          if (needmask) {
            int jgl = jbase + ct * 16 + nn;
            int igl = i0w + qd * 4 + r;
            if (jgl > igl) tv = -3.0e38f;
          }
          tt[ct][r] = tv;
        }
#pragma unroll
      for (int r = 0; r < 4; ++r) {
        float mr = fmaxf(fmaxf(tt[0][r], tt[1][r]), fmaxf(tt[2][r], tt[3][r]));
        mr = rowmax16(mr);
        float mn = fmaxf(m[r], mr);
        float alpha = EXP2F(m[r] - mn);
        m[r] = mn;
        float ps = 0.0f;
#pragma unroll
        for (int ct = 0; ct < 4; ++ct) {
          float p = EXP2F(tt[ct][r] - mn);
          tt[ct][r] = p;
          ps += p;
        }
        l[r] = l[r] * alpha + ps;
#pragma unroll
        for (int vt = 0; vt < 8; ++vt) o[vt][r] *= alpha;
      }
#pragma unroll
      for (int ct = 0; ct < 4; ++ct)
#pragma unroll
        for (int r = 0; r < 4; ++r)
          smem[P0 + (w * 16 + qd * 4 + r) * PS_LD + ct * 16 + nn] = f2bf(tt[ct][r]);
    }

#pragma unroll
    for (int ks2 = 0; ks2 < 2; ++ks2) {
      short8 a = *(const short8*)(smem + P0 + (w * 16 + nn) * PS_LD + ks2 * 32 + qd * 8);
#pragma unroll
      for (int vt = 0; vt < 8; ++vt) {
        const int p = 16 * vt + rb + ((2 * vt + nn + hh) & 7);
        short8 vbf = *(const short8*)(smem + vb + p * VS_LD + ks2 * 32 + qd * 8);
        o[vt] = __builtin_amdgcn_mfma_f32_16x16x32_bf16(a, vbf, o[vt], 0, 0, 0);
      }
    }

    if (more) stage_write(cur ^ 1, jt + 1);
    __syncthreads();
  }

#pragma unroll
  for (int r = 0; r < 4; ++r) l[r] = rowsum16(l[r]);

  if (direct) {
    float* Ob = Out + ((size_t)b * SEQ_N + i0w) * DIM_V;
#pragma unroll
    for (int r = 0; r < 4; ++r) {
      float inv = 1.0f / l[r];
      int row = qd * 4 + r;
#pragma unroll
      for (int vt = 0; vt < 8; ++vt)
        Ob[(size_t)row * DIM_V + vt * 16 + nn] = o[vt][r] * inv;
    }
  } else {
    const int p = b * 16 + (rt - 16);
    const int slot = p * 2 + c;
    float* Op = ws + (size_t)slot * 64 * 128;
#pragma unroll
    for (int r = 0; r < 4; ++r) {
      int row = w * 16 + qd * 4 + r;
#pragma unroll
      for (int vt = 0; vt < 8; ++vt)
        Op[(size_t)row * 128 + vt * 16 + nn] = o[vt][r];
    }
    if (nn == 0) {
#pragma unroll
      for (int r = 0; r < 4; ++r) {
        int row = w * 16 + qd * 4 + r;
        ws[WS_M_OFF + slot * 64 + row] = m[r];
        ws[WS_L_OFF + slot * 64 + row] = l[r];
      }
    }
  }
}

__global__ __launch_bounds__(256, 2)
void fa_chunk(const float* __restrict__ Q, const float* __restrict__ K,
              const float* __restrict__ Vg, const int* __restrict__ kpl,
              const int* __restrict__ amask, float* __restrict__ Out,
              float* __restrict__ ws) {
  __shared__ __align__(16) ushort_t smem[SMEM_ELEMS];
  const int bx = blockIdx.x;
  const int b  = bx & 15;
  const int u  = bx >> 4;
  int rt, c;
  if (u < 16)      { rt = 16 + u; c = 0; }
  else if (u < 32) { rt = 47 - u; c = 1; }
  else             { rt = 47 - u; c = 0; }
  const int flag   = amask[0];
  const int mlimit = SEQ_M - kpl[b];
  const int ntiles = flag ? (rt + 1) : (SEQ_M / BC);
  const int jt_lo  = (c == 1) ? 16 : 0;
  const int jt_hi  = (c == 0 && rt >= 16) ? 16 : ntiles;
  process_chunk(Q, K, Vg, Out, ws, smem, b, rt, jt_lo, jt_hi, mlimit, flag, c, rt < 16);
}

__global__ __launch_bounds__(256)
void fa_merge(const float* __restrict__ ws, float* __restrict__ Out) {
  const int w = threadIdx.x >> 6, lane = threadIdx.x & 63;
  const int rowid = blockIdx.x * 4 + w;
  const int p = rowid >> 6, rr = rowid & 63;
  const int b = p >> 4, rt = 16 + (p & 15);
  float m1 = ws[WS_M_OFF + (p * 2 + 0) * 64 + rr];
  float l1 = ws[WS_L_OFF + (p * 2 + 0) * 64 + rr];
  float m2 = ws[WS_M_OFF + (p * 2 + 1) * 64 + rr];
  float l2 = ws[WS_L_OFF + (p * 2 + 1) * 64 + rr];
  float M  = fmaxf(m1, m2);
  float a1 = EXP2F(m1 - M), a2 = EXP2F(m2 - M);
  float inv = 1.0f / (l1 * a1 + l2 * a2);
  const float* O1 = ws + ((size_t)(p * 2 + 0) * 64 + rr) * 128;
  const float* O2 = ws + ((size_t)(p * 2 + 1) * 64 + rr) * 128;
  float2 x1 = *(const float2*)(O1 + lane * 2);
  float2 x2 = *(const float2*)(O2 + lane * 2);
  float2 r;
  r.x = (x1.x * a1 + x2.x * a2) * inv;
  r.y = (x1.y * a1 + x2.y * a2) * inv;
  *(float2*)(Out + ((size_t)b * SEQ_N + rt * 64 + rr) * 128 + lane * 2) = r;
}

__global__ __launch_bounds__(256, 2)
void fa_paired(const float* __restrict__ Q, const float* __restrict__ K,
               const float* __restrict__ Vg, const int* __restrict__ kpl,
               const int* __restrict__ amask, float* __restrict__ Out) {
  __shared__ __align__(16) ushort_t smem[SMEM_ELEMS];
  const int bx = blockIdx.x;
  const int b  = bx & 15;
  const int pp = bx >> 4;
  const int flag   = amask[0];
  const int mlimit = SEQ_M - kpl[b];
#pragma unroll 1
  for (int ph = 0; ph < 2; ++ph) {
    const int rt = ph ? (31 - pp) : pp;
    const int ntiles = flag ? (rt + 1) : (SEQ_M / BC);
    process_chunk(Q, K, Vg, Out, nullptr, smem, b, rt, 0, ntiles, mlimit, flag, 0, true);
  }
}

extern "C" void kernel_launch(void* const* d_in, const int* in_sizes, int n_in,
                              void* d_out, int out_size, void* d_ws, size_t ws_size,
                              hipStream_t stream) {
  const float* Q   = (const float*)d_in[0];
  const float* K   = (const float*)d_in[1];
  const float* V   = (const float*)d_in[2];
  const int* kpl   = (const int*)d_in[3];
  const int* amask = (const int*)d_in[4];
  float* O         = (float*)d_out;
  float* ws        = (float*)d_ws;

  if (ws_size >= (size_t)WS2_FLOATS * 4) {
    hipLaunchKernelGGL(prep2, dim3(3072), dim3(256), 0, stream, K, V, kpl, ws);
    hipLaunchKernelGGL(fa2, dim3(1024), dim3(256), 0, stream, Q, amask, O, ws);
    hipLaunchKernelGGL(fa2_merge, dim3(8192), dim3(256), 0, stream, O, ws);
  } else if (ws_size >= (size_t)WS_FLOATS * 4) {
    hipLaunchKernelGGL(fa_chunk, dim3(768), dim3(256), 0, stream, Q, K, V, kpl, amask, O, ws);
    hipLaunchKernelGGL(fa_merge, dim3(4096), dim3(256), 0, stream, ws, O);
  } else {
    hipLaunchKernelGGL(fa_paired, dim3(256), dim3(256), 0, stream, Q, K, V, kpl, amask, O);
  }
}